// Round 1
// baseline (281.496 us; speedup 1.0000x reference)
//
#include <hip/hip_runtime.h>

#define C_     64
#define H_     40
#define W_     40
#define KS     11
#define HP     30          // H_ - KS + 1
#define NB     4
#define NL     900         // HP*HP
#define NDISP  59          // 2*(HP-1)+1 displacements per axis
#define EPSF   1e-4f

// ---------------------------------------------------------------------------
// Kernel 1: inverse L2 norms of im1 patches.  invnorm[b*NL + l] = 1/max(||p1||,eps)
// ---------------------------------------------------------------------------
__global__ __launch_bounds__(128)
void k_norm(const float* __restrict__ im1, float* __restrict__ invnorm) {
    const int l  = blockIdx.x;       // 0..899
    const int b  = blockIdx.y;
    const int ly = l / HP, lx = l - ly * HP;
    const int tid = threadIdx.x;
    const float* base = im1 + b * C_ * H_ * W_;
    float ss = 0.f;
    for (int d = tid; d < C_ * KS * KS; d += 128) {
        int c  = d / (KS * KS);
        int rs = d - c * (KS * KS);
        int r  = rs / KS, s = rs - r * KS;
        float v = base[c * H_ * W_ + (ly + r) * W_ + (lx + s)];
        ss += v * v;
    }
    #pragma unroll
    for (int off = 32; off >= 1; off >>= 1) ss += __shfl_down(ss, off, 64);
    __shared__ float partial[2];
    if ((tid & 63) == 0) partial[tid >> 6] = ss;
    __syncthreads();
    if (tid == 0) {
        float tot = partial[0] + partial[1];
        invnorm[b * NL + l] = 1.f / fmaxf(sqrtf(tot), EPSF);
    }
}

// ---------------------------------------------------------------------------
// build one correlation Gram plane G_y[x2][x1] = sum_c im2[c,y,x2]*im1[c,y+dy,x1]
// into ring[y % KS].  Called uniformly by all 256 threads.
// ---------------------------------------------------------------------------
__device__ __forceinline__
void build_plane(const float* __restrict__ im1b, const float* __restrict__ im2b,
                 int y, int dy, int tid,
                 float ring[KS][H_ * W_], float R2[C_][W_], float R1[C_][W_]) {
    // stage the two rows (64 channels x 40 px each), coalesced
    for (int i = tid; i < C_ * W_; i += 256) {
        int c = i / W_, x = i - c * W_;
        R2[c][x] = im2b[c * H_ * W_ + y * W_ + x];
        R1[c][x] = im1b[c * H_ * W_ + (y + dy) * W_ + x];
    }
    __syncthreads();
    // 40x40 = 200 tasks of 2x4 register tiles over K=64
    if (tid < 200) {
        const int t2 = tid / 10;
        const int x2 = 2 * t2;
        const int x1 = 4 * (tid - t2 * 10);
        float a00 = 0.f, a01 = 0.f, a02 = 0.f, a03 = 0.f;
        float a10 = 0.f, a11 = 0.f, a12 = 0.f, a13 = 0.f;
        #pragma unroll 8
        for (int c = 0; c < C_; ++c) {
            const float2 av = *(const float2*)&R2[c][x2];
            const float4 bv = *(const float4*)&R1[c][x1];
            a00 += av.x * bv.x; a01 += av.x * bv.y; a02 += av.x * bv.z; a03 += av.x * bv.w;
            a10 += av.y * bv.x; a11 += av.y * bv.y; a12 += av.y * bv.z; a13 += av.y * bv.w;
        }
        float* pl = ring[y % KS];
        *(float4*)&pl[x2 * W_ + x1]       = make_float4(a00, a01, a02, a03);
        *(float4*)&pl[(x2 + 1) * W_ + x1] = make_float4(a10, a11, a12, a13);
    }
    __syncthreads();
}

// ---------------------------------------------------------------------------
// Kernel 2: per (b, dy) block — ring-buffered box-filtered correlation, max over dx,
// merged into global uint-keyed accumulator.
// ---------------------------------------------------------------------------
__global__ __launch_bounds__(256)
void k_main(const float* __restrict__ im1, const float* __restrict__ im2,
            const float* __restrict__ invnorm, unsigned int* __restrict__ keys) {
    const int dy  = (int)blockIdx.x - (HP - 1);
    const int b   = blockIdx.y;
    const int tid = threadIdx.x;
    const int pyLo = (dy < 0) ? -dy : 0;
    const int pyHi = (dy > 0) ? (HP - 1 - dy) : (HP - 1);

    __shared__ float ring[KS][H_ * W_];   // 11 Gram planes, 70.4 KB
    __shared__ float csum[H_ * W_];       // column sums over r, 6.4 KB
    __shared__ float R2[C_][W_];          // im2 row staging, 10.24 KB
    __shared__ float R1[C_][W_];          // im1 row staging, 10.24 KB
    __shared__ unsigned int pxKey[HP];

    const float* im1b = im1 + b * C_ * H_ * W_;
    const float* im2b = im2 + b * C_ * H_ * W_;

    // prologue: build planes y = pyLo .. pyLo+10
    for (int y = pyLo; y < pyLo + KS; ++y)
        build_plane(im1b, im2b, y, dy, tid, ring, R2, R1);

    // initial column sum over the 11 planes
    for (int e = tid; e < H_ * W_; e += 256) {
        float s = 0.f;
        #pragma unroll
        for (int r = 0; r < KS; ++r) s += ring[(pyLo + r) % KS][e];
        csum[e] = s;
    }
    __syncthreads();

    for (int py = pyLo; ; ++py) {
        if (tid < HP) pxKey[tid] = 0u;   // 0 is below every real key
        __syncthreads();

        const int ly = py + dy;
        const float* invrow = invnorm + b * NL + ly * HP;
        // diagonal 11-tap sums: tasks (dxI, px)
        for (int t = tid; t < NDISP * HP; t += 256) {
            int dxI = t / HP;
            int px  = t - dxI * HP;
            int dx  = dxI - (HP - 1);
            int lx  = px + dx;
            if ((unsigned)lx < HP) {
                int bse = px * W_ + px + dx;
                float s = 0.f;
                #pragma unroll
                for (int sr = 0; sr < KS; ++sr) s += csum[bse + sr * (W_ + 1)];
                float cand = s * invrow[lx];
                unsigned int ub = __float_as_uint(cand);
                unsigned int k  = (ub & 0x80000000u) ? ~ub : (ub | 0x80000000u);
                atomicMax(&pxKey[px], k);
            }
        }
        __syncthreads();
        if (tid < HP) atomicMax(&keys[b * NL + py * HP + tid], pxKey[tid]);

        if (py == pyHi) break;

        // slide the column-sum window: csum += G[py+11] - G[py]
        const int slot = py % KS;
        for (int e = tid; e < H_ * W_; e += 256) csum[e] -= ring[slot][e];
        __syncthreads();
        build_plane(im1b, im2b, py + KS, dy, tid, ring, R2, R1);  // overwrites same slot
        for (int e = tid; e < H_ * W_; e += 256) csum[e] += ring[slot][e];
        __syncthreads();
    }
}

// ---------------------------------------------------------------------------
// Kernel 3: decode monotone uint keys back to float
// ---------------------------------------------------------------------------
__global__ __launch_bounds__(256)
void k_decode(const unsigned int* __restrict__ keys, float* __restrict__ out) {
    int i = blockIdx.x * 256 + threadIdx.x;
    if (i < NB * NL) {
        unsigned int k = keys[i];
        unsigned int u = (k & 0x80000000u) ? (k ^ 0x80000000u) : ~k;
        out[i] = __uint_as_float(u);
    }
}

extern "C" void kernel_launch(void* const* d_in, const int* in_sizes, int n_in,
                              void* d_out, int out_size, void* d_ws, size_t ws_size,
                              hipStream_t stream) {
    const float* im1 = (const float*)d_in[0];
    const float* im2 = (const float*)d_in[1];
    unsigned int* keys = (unsigned int*)d_ws;
    float* invnorm = (float*)d_ws + NB * NL;

    hipMemsetAsync(d_ws, 0, NB * NL * sizeof(unsigned int), stream);
    k_norm<<<dim3(NL, NB), 128, 0, stream>>>(im1, invnorm);
    k_main<<<dim3(NDISP, NB), 256, 0, stream>>>(im1, im2, invnorm, keys);
    k_decode<<<(NB * NL + 255) / 256, 256, 0, stream>>>(keys, (float*)d_out);
}

// Round 2
// 192.351 us; speedup vs baseline: 1.4634x; 1.4634x over previous
//
#include <hip/hip_runtime.h>

#define C_     64
#define H_     40
#define W_     40
#define KS     11
#define HP     30          // H_ - KS + 1
#define NB     4
#define NL     900         // HP*HP
#define NDISP  59          // 2*(HP-1)+1
#define EPSF   1e-4f
#define P_CH   6           // output rows per chunk
#define MAXPL  16          // P_CH + KS - 1

typedef _Float16 half2_t __attribute__((ext_vector_type(2)));
typedef _Float16 half4_t __attribute__((ext_vector_type(4)));
typedef _Float16 half8_t __attribute__((ext_vector_type(8)));

union H8 { half8_t v; half2_t p[4]; };
union H4 { half4_t v; half2_t p[2]; };

__device__ __forceinline__ float fdot2f(half2_t a, half2_t b, float c) {
#if __has_builtin(__builtin_amdgcn_fdot2)
    return __builtin_amdgcn_fdot2(a, b, c, false);
#else
    return c + (float)a[0] * (float)b[0] + (float)a[1] * (float)b[1];
#endif
}

// ---------------------------------------------------------------------------
// Kernel 1: separable box filter for inverse patch norms of im1.
// ---------------------------------------------------------------------------
__global__ __launch_bounds__(1024)
void k_norm(const float* __restrict__ im1, float* __restrict__ invnorm) {
    const int b = blockIdx.x;
    const int tid = threadIdx.x;
    __shared__ float ssq[H_ * W_];
    __shared__ float colsum[HP * W_];
    const float* base = im1 + b * C_ * H_ * W_;
    for (int e = tid; e < H_ * W_; e += 1024) {
        float s = 0.f;
        #pragma unroll 8
        for (int c = 0; c < C_; ++c) { float v = base[c * H_ * W_ + e]; s += v * v; }
        ssq[e] = s;
    }
    __syncthreads();
    for (int t = tid; t < HP * W_; t += 1024) {
        int yy = t / W_, x = t - yy * W_;
        float s = 0.f;
        #pragma unroll
        for (int r = 0; r < KS; ++r) s += ssq[(yy + r) * W_ + x];
        colsum[t] = s;
    }
    __syncthreads();
    for (int t = tid; t < NL; t += 1024) {
        int ly = t / HP, lx = t - ly * HP;
        float s = 0.f;
        #pragma unroll
        for (int sx = 0; sx < KS; ++sx) s += colsum[ly * W_ + lx + sx];
        invnorm[b * NL + t] = 1.f / fmaxf(sqrtf(s), EPSF);
    }
}

// ---------------------------------------------------------------------------
// Kernel 2: per (b, dy, py-chunk) block.
// ---------------------------------------------------------------------------
__global__ __launch_bounds__(256, 2)
void k_main(const float* __restrict__ im1, const float* __restrict__ im2,
            const float* __restrict__ invnorm, unsigned int* __restrict__ keys) {
    const int chunk = blockIdx.x;                 // 0..4
    const int dy    = (int)blockIdx.y - (HP - 1); // -29..29
    const int b     = blockIdx.z;
    const int ady   = dy < 0 ? -dy : dy;
    const int rows  = HP - ady;
    const int nCh   = (rows + P_CH - 1) / P_CH;
    if (chunk >= nCh) return;
    const int pyLo = (dy < 0) ? -dy : 0;
    const int py0  = pyLo + chunk * P_CH;
    const int P    = min(P_CH, pyLo + rows - py0);
    const int nPl  = P + KS - 1;                  // planes y = py0 .. py0+nPl-1
    const int tid  = threadIdx.x;

    __shared__ __align__(16) _Float16 planes[MAXPL][H_ * W_]; // 51.2 KB
    __shared__ float csum[H_ * W_];                            // 6.4 KB
    __shared__ __align__(16) _Float16 Sg[2][2][C_ / 2][2 * W_]; // 20.5 KB staging
    __shared__ unsigned int pxKey[HP];

    const float* im1b = im1 + b * C_ * H_ * W_;
    const float* im2b = im2 + b * C_ * H_ * W_;

    // thread's GEMM tile (2 x2-rows, 4 x1-cols); 200 active
    const int t2 = tid / 10;
    const int x2 = 2 * t2;
    const int x1 = 4 * (tid - 10 * t2);

    // ---- stage rows for plane y into buffer buf (channel-pair packed f16) ----
    auto stage = [&](int buf, int y) {
        for (int i = tid; i < C_ * W_; i += 256) {
            int c = i / W_, x = i - c * W_;
            float v2 = im2b[c * H_ * W_ + y * W_ + x];
            float v1 = im1b[c * H_ * W_ + (y + dy) * W_ + x];
            Sg[buf][0][c >> 1][2 * x + (c & 1)] = (_Float16)v2;
            Sg[buf][1][c >> 1][2 * x + (c & 1)] = (_Float16)v1;
        }
    };

    stage(0, py0);
    __syncthreads();
    for (int p = 0; p < nPl; ++p) {
        if (p + 1 < nPl) stage((p + 1) & 1, py0 + p + 1);
        if (tid < 200) {
            const int buf = p & 1;
            float acc[2][4] = {{0.f, 0.f, 0.f, 0.f}, {0.f, 0.f, 0.f, 0.f}};
            #pragma unroll 8
            for (int k = 0; k < C_ / 2; ++k) {
                H4 a;  a.v  = *(const half4_t*)&Sg[buf][0][k][2 * x2];
                H8 bb; bb.v = *(const half8_t*)&Sg[buf][1][k][2 * x1];
                #pragma unroll
                for (int j = 0; j < 4; ++j) {
                    acc[0][j] = fdot2f(a.p[0], bb.p[j], acc[0][j]);
                    acc[1][j] = fdot2f(a.p[1], bb.p[j], acc[1][j]);
                }
            }
            half4_t r0 = { (_Float16)acc[0][0], (_Float16)acc[0][1], (_Float16)acc[0][2], (_Float16)acc[0][3] };
            half4_t r1 = { (_Float16)acc[1][0], (_Float16)acc[1][1], (_Float16)acc[1][2], (_Float16)acc[1][3] };
            *(half4_t*)&planes[p][x2 * W_ + x1]       = r0;
            *(half4_t*)&planes[p][(x2 + 1) * W_ + x1] = r1;
        }
        __syncthreads();
    }

    // ---- per output row: rebuild csum from 11 planes, then diagonal stage ----
    for (int i = 0; i < P; ++i) {
        if (tid < HP) pxKey[tid] = 0u;
        if (tid < 200) {
            float s[8] = {0.f, 0.f, 0.f, 0.f, 0.f, 0.f, 0.f, 0.f};
            #pragma unroll
            for (int r = 0; r < KS; ++r) {
                H8 q; q.v = *(const half8_t*)&planes[i + r][tid * 8];
                #pragma unroll
                for (int j = 0; j < 4; ++j) {
                    s[2 * j]     += (float)q.p[j][0];
                    s[2 * j + 1] += (float)q.p[j][1];
                }
            }
            #pragma unroll
            for (int j = 0; j < 8; ++j) csum[tid * 8 + j] = s[j];
        }
        __syncthreads();

        const int py = py0 + i;
        const int ly = py + dy;
        const float* invrow = invnorm + b * NL + ly * HP;
        for (int t = tid; t < NDISP * HP; t += 256) {
            int dxI = t / HP;
            int px  = t - dxI * HP;
            int dx  = dxI - (HP - 1);
            int lx  = px + dx;
            if ((unsigned)lx < HP) {
                int bse = px * (W_ + 1) + dx;   // px*W + (px+dx)
                float s = 0.f;
                #pragma unroll
                for (int sr = 0; sr < KS; ++sr) s += csum[bse + sr * (W_ + 1)];
                float cand = s * invrow[lx];
                unsigned int ub = __float_as_uint(cand);
                unsigned int k  = (ub & 0x80000000u) ? ~ub : (ub | 0x80000000u);
                atomicMax(&pxKey[px], k);
            }
        }
        __syncthreads();
        if (tid < HP) atomicMax(&keys[b * NL + py * HP + tid], pxKey[tid]);
        __syncthreads();
    }
}

// ---------------------------------------------------------------------------
// Kernel 3: decode monotone uint keys back to float
// ---------------------------------------------------------------------------
__global__ __launch_bounds__(256)
void k_decode(const unsigned int* __restrict__ keys, float* __restrict__ out) {
    int i = blockIdx.x * 256 + threadIdx.x;
    if (i < NB * NL) {
        unsigned int k = keys[i];
        unsigned int u = (k & 0x80000000u) ? (k ^ 0x80000000u) : ~k;
        out[i] = __uint_as_float(u);
    }
}

extern "C" void kernel_launch(void* const* d_in, const int* in_sizes, int n_in,
                              void* d_out, int out_size, void* d_ws, size_t ws_size,
                              hipStream_t stream) {
    const float* im1 = (const float*)d_in[0];
    const float* im2 = (const float*)d_in[1];
    unsigned int* keys = (unsigned int*)d_ws;
    float* invnorm = (float*)d_ws + NB * NL;

    hipMemsetAsync(d_ws, 0, NB * NL * sizeof(unsigned int), stream);
    k_norm<<<NB, 1024, 0, stream>>>(im1, invnorm);
    k_main<<<dim3(5, NDISP, NB), 256, 0, stream>>>(im1, im2, invnorm, keys);
    k_decode<<<(NB * NL + 255) / 256, 256, 0, stream>>>(keys, (float*)d_out);
}

// Round 3
// 149.175 us; speedup vs baseline: 1.8870x; 1.2894x over previous
//
#include <hip/hip_runtime.h>

#define C_    64
#define H_    40
#define W_    40
#define KS    11
#define HP    30          // H_ - KS + 1
#define NB    4
#define NL    900         // HP*HP
#define ND    59          // 2*(HP-1)+1
#define EPSF  1e-4f
#define PCH   6           // output rows per chunk
#define MAXPL 16          // PCH + KS - 1
#define SCW   65          // scratch row stride in floats (odd -> conflict-free)
#define NINF  -3.4e38f

typedef _Float16 f16x8 __attribute__((ext_vector_type(8)));
typedef float    f32x4 __attribute__((ext_vector_type(4)));

// ---------------------------------------------------------------------------
// k_norm: one block per (ly, b). invnorm[b][ly][lx] = 1/max(||patch1||, eps)
// ---------------------------------------------------------------------------
__global__ __launch_bounds__(256)
void k_norm(const float* __restrict__ im1, float* __restrict__ invnorm) {
    const int ly = blockIdx.x, b = blockIdx.y;
    const int tid = threadIdx.x;
    __shared__ float colsq[KS * W_];
    __shared__ float colsum[W_];
    const float* base = im1 + b * C_ * H_ * W_;
    for (int i = tid; i < KS * W_; i += 256) {
        int r = i / W_, x = i - r * W_;
        const float* p = base + (ly + r) * W_ + x;
        float s = 0.f;
        #pragma unroll 8
        for (int c = 0; c < C_; ++c) { float v = p[c * H_ * W_]; s += v * v; }
        colsq[i] = s;
    }
    __syncthreads();
    if (tid < W_) {
        float s = 0.f;
        #pragma unroll
        for (int r = 0; r < KS; ++r) s += colsq[r * W_ + tid];
        colsum[tid] = s;
    }
    __syncthreads();
    if (tid < HP) {
        float s = 0.f;
        #pragma unroll
        for (int sx = 0; sx < KS; ++sx) s += colsum[tid + sx];
        invnorm[b * NL + ly * HP + tid] = 1.f / fmaxf(sqrtf(s), EPSF);
    }
}

// ---------------------------------------------------------------------------
// k_main: one block per (chunk, dy, b). MFMA plane-GEMMs + sliding box filter.
// ---------------------------------------------------------------------------
__global__ __launch_bounds__(256, 2)
void k_main(const float* __restrict__ im1, const float* __restrict__ im2,
            const float* __restrict__ invnorm, unsigned int* __restrict__ keys) {
    const int chunk = blockIdx.x;
    const int dy = (int)blockIdx.y - (HP - 1);
    const int b = blockIdx.z;
    const int ady = dy < 0 ? -dy : dy;
    const int rows = HP - ady;
    if (chunk * PCH >= rows) return;
    const int pyLo = dy < 0 ? -dy : 0;
    const int py0 = pyLo + chunk * PCH;
    const int P = min(PCH, rows - chunk * PCH);
    const int nPl = P + KS - 1;
    const int tid = threadIdx.x;
    const int w = tid >> 6, L = tid & 63, lq = L >> 4, lr = L & 15;

    __shared__ __align__(16) _Float16 planes[MAXPL][H_ * W_]; // 51.2 KB
    __shared__ __align__(16) float csum[H_ * W_];              // 6.4 KB
    __shared__ __align__(16) _Float16 Astg[8][48][8];          // 6.1 KB (im2 row)
    __shared__ __align__(16) _Float16 Bstg[8][48][8];          // 6.1 KB (im1 row)
    __shared__ float scratch[HP * SCW];                        // 7.8 KB
    __shared__ float partials[120];
    __shared__ float sInv[HP];

    const float* im1b = im1 + b * C_ * H_ * W_;
    const float* im2b = im2 + b * C_ * H_ * W_;

    // zero-fill the x = 40..47 pad region once (A and B, all octets)
    if (tid < 128) {
        int arr = tid >> 6, r = tid & 63;
        int oct = r >> 3, x = 40 + (r & 7);
        f16x8 z = {};
        *(f16x8*)((arr ? Bstg : Astg)[oct][x]) = z;
    }

    // ---------------- plane GEMMs: planes[p] = R2(y)^T R1(y+dy) --------------
    for (int p = 0; p < nPl; ++p) {
        const int y = py0 + p;
        // stage rows channel-octet-packed: stg[oct][x][j] = img[oct*8+j][row][x]
        for (int t = tid; t < 640; t += 256) {
            int arr = t >= 320;
            int r = arr ? t - 320 : t;
            int oct = r / 40, x = r - oct * 40;
            const float* pc = (arr ? (im1b + (y + dy) * W_) : (im2b + y * W_))
                              + oct * 8 * H_ * W_ + x;
            f16x8 h;
            #pragma unroll
            for (int j = 0; j < 8; ++j) h[j] = (_Float16)pc[j * H_ * W_];
            *(f16x8*)((arr ? Bstg : Astg)[oct][x]) = h;
        }
        __syncthreads();
        // 9 tiles of 16x16 over padded 48x48, K=64 (2 MFMAs each)
        for (int t = w; t < 9; t += 4) {
            int mt = t / 3, nt = t - 3 * mt;
            f16x8 a0 = *(const f16x8*)(Astg[lq][mt * 16 + lr]);
            f16x8 b0 = *(const f16x8*)(Bstg[lq][nt * 16 + lr]);
            f16x8 a1 = *(const f16x8*)(Astg[4 + lq][mt * 16 + lr]);
            f16x8 b1 = *(const f16x8*)(Bstg[4 + lq][nt * 16 + lr]);
            f32x4 acc = {0.f, 0.f, 0.f, 0.f};
            acc = __builtin_amdgcn_mfma_f32_16x16x32_f16(a0, b0, acc, 0, 0, 0);
            acc = __builtin_amdgcn_mfma_f32_16x16x32_f16(a1, b1, acc, 0, 0, 0);
            int x1 = nt * 16 + lr;                 // N = x1 (col = lane&15)
            if (x1 < W_) {
                int x2b = mt * 16 + lq * 4;        // M = x2 (row = quad*4+reg)
                #pragma unroll
                for (int rg = 0; rg < 4; ++rg) {
                    int x2 = x2b + rg;
                    if (x2 < W_) planes[p][x2 * W_ + x1] = (_Float16)acc[rg];
                }
            }
        }
        __syncthreads();
    }

    // ---------------- box filter: per output row ----------------------------
    for (int i = 0; i < P; ++i) {
        const int py = py0 + i;
        const int ly = py + dy;
        // step 1: csum init (i==0) or slide; lanes 224.. load invnorm row
        if (tid < 200) {
            float4* c4 = (float4*)(csum + tid * 8);
            if (i == 0) {
                float s[8] = {0.f, 0.f, 0.f, 0.f, 0.f, 0.f, 0.f, 0.f};
                #pragma unroll
                for (int r = 0; r < KS; ++r) {
                    f16x8 q = *(const f16x8*)(planes[r] + tid * 8);
                    #pragma unroll
                    for (int j = 0; j < 8; ++j) s[j] += (float)q[j];
                }
                c4[0] = make_float4(s[0], s[1], s[2], s[3]);
                c4[1] = make_float4(s[4], s[5], s[6], s[7]);
            } else {
                f16x8 qa = *(const f16x8*)(planes[i + 10] + tid * 8);
                f16x8 qs = *(const f16x8*)(planes[i - 1] + tid * 8);
                float4 v0 = c4[0], v1 = c4[1];
                v0.x += (float)qa[0] - (float)qs[0];
                v0.y += (float)qa[1] - (float)qs[1];
                v0.z += (float)qa[2] - (float)qs[2];
                v0.w += (float)qa[3] - (float)qs[3];
                v1.x += (float)qa[4] - (float)qs[4];
                v1.y += (float)qa[5] - (float)qs[5];
                v1.z += (float)qa[6] - (float)qs[6];
                v1.w += (float)qa[7] - (float)qs[7];
                c4[0] = v0; c4[1] = v1;
            }
        } else if (tid >= 224 && tid < 224 + HP) {
            sInv[tid - 224] = invnorm[b * NL + ly * HP + (tid - 224)];
        }
        __syncthreads();
        // step 2: diagonal 11-tap running sums, 6-px groups per (pg, dx) task
        for (int t = tid; t < 5 * ND; t += 256) {
            int pg = t / ND, dxI = t - ND * pg;
            int dx = dxI - (HP - 1), pxb = 6 * pg;
            #pragma unroll
            for (int u = 0; u < 6; ++u) scratch[(pxb + u) * SCW + dxI] = NINF;
            int u0 = max(0, -dx - pxb), u1 = min(5, (HP - 1) - dx - pxb);
            if (u0 <= u1) {
                const float* cp = csum + dx;   // e = (pxb+u+s)*41 + dx
                float run = 0.f;
                #pragma unroll
                for (int s = 0; s < KS; ++s) run += cp[(pxb + u0 + s) * (W_ + 1)];
                int u = u0;
                for (;;) {
                    scratch[(pxb + u) * SCW + dxI] = run * sInv[pxb + u + dx];
                    if (++u > u1) break;
                    run += cp[(pxb + u + 10) * (W_ + 1)] - cp[(pxb + u - 1) * (W_ + 1)];
                }
            }
        }
        __syncthreads();
        // step 3: partial max over dx (4 threads per px)
        if (tid < 120) {
            int px = tid >> 2, q = tid & 3;
            float m = NINF;
            int d0 = q * 15, d1 = min(d0 + 15, ND);
            for (int d = d0; d < d1; ++d) m = fmaxf(m, scratch[px * SCW + d]);
            partials[tid] = m;
        }
        __syncthreads();
        // step 4: final max + monotone-key global atomic
        if (tid < HP) {
            float m = fmaxf(fmaxf(partials[tid * 4], partials[tid * 4 + 1]),
                            fmaxf(partials[tid * 4 + 2], partials[tid * 4 + 3]));
            unsigned int ub = __float_as_uint(m);
            unsigned int k = (ub & 0x80000000u) ? ~ub : (ub | 0x80000000u);
            atomicMax(&keys[b * NL + py * HP + tid], k);
        }
        __syncthreads();
    }
}

// ---------------------------------------------------------------------------
// k_decode: monotone uint keys -> float output
// ---------------------------------------------------------------------------
__global__ __launch_bounds__(256)
void k_decode(const unsigned int* __restrict__ keys, float* __restrict__ out) {
    int i = blockIdx.x * 256 + threadIdx.x;
    if (i < NB * NL) {
        unsigned int k = keys[i];
        unsigned int u = (k & 0x80000000u) ? (k ^ 0x80000000u) : ~k;
        out[i] = __uint_as_float(u);
    }
}

extern "C" void kernel_launch(void* const* d_in, const int* in_sizes, int n_in,
                              void* d_out, int out_size, void* d_ws, size_t ws_size,
                              hipStream_t stream) {
    const float* im1 = (const float*)d_in[0];
    const float* im2 = (const float*)d_in[1];
    unsigned int* keys = (unsigned int*)d_ws;
    float* invnorm = (float*)d_ws + NB * NL;

    hipMemsetAsync(d_ws, 0, NB * NL * sizeof(unsigned int), stream);
    k_norm<<<dim3(HP, NB), 256, 0, stream>>>(im1, invnorm);
    k_main<<<dim3(5, ND, NB), 256, 0, stream>>>(im1, im2, invnorm, keys);
    k_decode<<<(NB * NL + 255) / 256, 256, 0, stream>>>(keys, (float*)d_out);
}

// Round 4
// 110.268 us; speedup vs baseline: 2.5528x; 1.3528x over previous
//
#include <hip/hip_runtime.h>

#define C_    64
#define H_    40
#define W_    40
#define KS    11
#define HP    30          // H_ - KS + 1
#define NB    4
#define NL    900         // HP*HP
#define ND    59          // 2*(HP-1)+1
#define EPSF  1e-4f
#define PCH   6           // output rows per chunk in k_box
#define SCW   65          // scratch row stride (odd -> conflict-free)
#define NINF  -3.4e38f
#define MPAD  1664        // 13*128, padded M=N
#define GSTEP 66600       // (40*MPAD + 40): plane-to-plane offset along the dy diagonal

typedef _Float16 f16x8 __attribute__((ext_vector_type(8)));
typedef float    f32x4 __attribute__((ext_vector_type(4)));

// ===========================================================================
// k_pack: fp32 images -> f16 octet-packed layout packed[img][b][oct][MPAD][8]
//         (img 0 = im2 = GEMM A/rows, img 1 = im1 = GEMM B/cols).
//         img==1 blocks also compute invnorm via separable box filter of ssq.
// ===========================================================================
__global__ __launch_bounds__(1024)
void k_pack(const float* __restrict__ im2, const float* __restrict__ im1,
            _Float16* __restrict__ packed, float* __restrict__ invnorm) {
    const int b = blockIdx.x, img = blockIdx.y;
    const int tid = threadIdx.x;
    __shared__ float ssq[1600];
    __shared__ float colsum[1200];
    const float* src = (img ? im1 : im2) + b * C_ * 1600;
    _Float16* dst = packed + ((size_t)img * NB + b) * (8 * MPAD * 8);
    for (int pos = tid; pos < MPAD; pos += 1024) {
        float ss = 0.f;
        #pragma unroll
        for (int oct = 0; oct < 8; ++oct) {
            f16x8 h = {};
            if (pos < 1600) {
                #pragma unroll
                for (int j = 0; j < 8; ++j) {
                    float v = src[(oct * 8 + j) * 1600 + pos];
                    h[j] = (_Float16)v;
                    ss += v * v;
                }
            }
            *(f16x8*)&dst[(oct * MPAD + pos) * 8] = h;
        }
        if (img == 1 && pos < 1600) ssq[pos] = ss;
    }
    if (img != 1) return;
    __syncthreads();
    for (int t = tid; t < HP * W_; t += 1024) {
        int yy = t / W_, x = t - yy * W_;
        float s = 0.f;
        #pragma unroll
        for (int r = 0; r < KS; ++r) s += ssq[(yy + r) * W_ + x];
        colsum[t] = s;
    }
    __syncthreads();
    for (int t = tid; t < NL; t += 1024) {
        int ly = t / HP, lx = t - ly * HP;
        float s = 0.f;
        #pragma unroll
        for (int sx = 0; sx < KS; ++sx) s += colsum[ly * W_ + lx + sx];
        invnorm[b * NL + t] = 1.f / fmaxf(sqrtf(s), EPSF);
    }
}

// ===========================================================================
// k_gram: G[b][m][n] = sum_c im2[c][m] * im1[c][n], f16 out, stride MPAD.
// 128x128 tile per block, 256 threads (4 waves x 64x64), K=64 single shot.
// ===========================================================================
__global__ __launch_bounds__(256, 3)
void k_gram(const _Float16* __restrict__ packed, _Float16* __restrict__ G) {
    const int i = blockIdx.x, j = blockIdx.y, b = blockIdx.z;
    int dd = i - j; if (dd < 0) dd = -dd;
    if (dd > 10) return;                     // |dy| <= 29 band only
    const int tid = threadIdx.x;
    const int w = tid >> 6, L = tid & 63, lq = L >> 4, lr = L & 15;

    __shared__ __align__(16) _Float16 smem[128 * 136];   // A(16K)+B(16K) / C overlay
    _Float16 (*As)[128][8] = (_Float16 (*)[128][8])smem;
    _Float16 (*Bs)[128][8] = (_Float16 (*)[128][8])(smem + 8192);

    const _Float16* pa = packed + (size_t)b * (8 * MPAD * 8);
    const _Float16* pb = packed + (size_t)(NB + b) * (8 * MPAD * 8);
    for (int t = tid; t < 1024; t += 256) {
        int oct = t >> 7, m = t & 127;
        *(f16x8*)&As[oct][m][0] = *(const f16x8*)&pa[(oct * MPAD + i * 128 + m) * 8];
        *(f16x8*)&Bs[oct][m][0] = *(const f16x8*)&pb[(oct * MPAD + j * 128 + m) * 8];
    }
    __syncthreads();

    const int mb = (w & 1) * 64, nb = (w >> 1) * 64;
    f16x8 a0[4], a1[4], b0[4], b1[4];
    #pragma unroll
    for (int q = 0; q < 4; ++q) {
        a0[q] = *(const f16x8*)&As[lq][mb + q * 16 + lr][0];
        a1[q] = *(const f16x8*)&As[4 + lq][mb + q * 16 + lr][0];
        b0[q] = *(const f16x8*)&Bs[lq][nb + q * 16 + lr][0];
        b1[q] = *(const f16x8*)&Bs[4 + lq][nb + q * 16 + lr][0];
    }
    f32x4 acc[4][4];
    #pragma unroll
    for (int mi = 0; mi < 4; ++mi)
        #pragma unroll
        for (int ni = 0; ni < 4; ++ni) {
            f32x4 c = {0.f, 0.f, 0.f, 0.f};
            c = __builtin_amdgcn_mfma_f32_16x16x32_f16(a0[mi], b0[ni], c, 0, 0, 0);
            c = __builtin_amdgcn_mfma_f32_16x16x32_f16(a1[mi], b1[ni], c, 0, 0, 0);
            acc[mi][ni] = c;
        }
    __syncthreads();   // frags are in regs; safe to overwrite smem with C
    // C layout: row (A/m) = quad*4+reg, col (B/n) = lane&15  [verified in R3]
    #pragma unroll
    for (int mi = 0; mi < 4; ++mi)
        #pragma unroll
        for (int ni = 0; ni < 4; ++ni)
            #pragma unroll
            for (int rg = 0; rg < 4; ++rg)
                smem[(mb + mi * 16 + lq * 4 + rg) * 136 + nb + ni * 16 + lr] =
                    (_Float16)acc[mi][ni][rg];
    __syncthreads();
    _Float16* Gb = G + (size_t)b * (MPAD * MPAD);
    for (int t = tid; t < 2048; t += 256) {
        int row = t >> 4, seg = t & 15;
        *(f16x8*)&Gb[(size_t)(i * 128 + row) * MPAD + j * 128 + seg * 8] =
            *(const f16x8*)&smem[row * 136 + seg * 8];
    }
}

// ===========================================================================
// k_box: per (chunk, dy, b) block — register-resident sliding column sums over
// G planes + diagonal 11-tap sums + max over dx, merged via monotone-uint keys.
// ===========================================================================
__global__ __launch_bounds__(256, 4)
void k_box(const _Float16* __restrict__ G, const float* __restrict__ invnorm,
           unsigned int* __restrict__ keys) {
    const int chunk = blockIdx.x;
    const int dy = (int)blockIdx.y - (HP - 1);
    const int b = blockIdx.z;
    const int ady = dy < 0 ? -dy : dy;
    const int rows = HP - ady;
    if (chunk * PCH >= rows) return;
    const int pyLo = dy < 0 ? -dy : 0;
    const int py0 = pyLo + chunk * PCH;
    const int P = min(PCH, rows - chunk * PCH);
    const int tid = threadIdx.x;

    __shared__ float csum[1600];
    __shared__ float scratch[HP * SCW];
    __shared__ float partials[120];
    __shared__ float sInv[HP];

    const _Float16* Gb = G + (size_t)b * (MPAD * MPAD);
    float s[8];
    const _Float16* base = nullptr;
    if (tid < 200) {
        int e = tid * 8, x2 = e / 40, x1 = e - x2 * 40;
        // plane p element: G[(py0+p)*40 + x2][(py0+p+dy)*40 + x1]
        base = Gb + (size_t)py0 * GSTEP + x2 * MPAD + dy * 40 + x1;
        #pragma unroll
        for (int j = 0; j < 8; ++j) s[j] = 0.f;
        for (int r = 0; r < KS; ++r) {
            f16x8 q = *(const f16x8*)(base + r * GSTEP);
            #pragma unroll
            for (int j = 0; j < 8; ++j) s[j] += (float)q[j];
        }
    }

    for (int i = 0; i < P; ++i) {
        const int py = py0 + i, ly = py + dy;
        if (tid < 200) {
            if (i > 0) {
                f16x8 qa = *(const f16x8*)(base + (i + 10) * GSTEP);
                f16x8 qs = *(const f16x8*)(base + (i - 1) * GSTEP);
                #pragma unroll
                for (int j = 0; j < 8; ++j) s[j] += (float)qa[j] - (float)qs[j];
            }
            float4* c4 = (float4*)(csum + tid * 8);
            c4[0] = make_float4(s[0], s[1], s[2], s[3]);
            c4[1] = make_float4(s[4], s[5], s[6], s[7]);
        } else if (tid >= 224 && tid < 224 + HP) {
            sInv[tid - 224] = invnorm[b * NL + ly * HP + (tid - 224)];
        }
        __syncthreads();
        // diagonal 11-tap running sums: task = (px-group of 6, dx)
        for (int t = tid; t < 5 * ND; t += 256) {
            int pg = t / ND, dxI = t - ND * pg;
            int dx = dxI - (HP - 1), pxb = 6 * pg;
            #pragma unroll
            for (int u = 0; u < 6; ++u) scratch[(pxb + u) * SCW + dxI] = NINF;
            int u0 = max(0, -dx - pxb), u1 = min(5, (HP - 1) - dx - pxb);
            if (u0 <= u1) {
                const float* cp = csum + dx;
                float run = 0.f;
                #pragma unroll
                for (int sr = 0; sr < KS; ++sr) run += cp[(pxb + u0 + sr) * (W_ + 1)];
                int u = u0;
                for (;;) {
                    scratch[(pxb + u) * SCW + dxI] = run * sInv[pxb + u + dx];
                    if (++u > u1) break;
                    run += cp[(pxb + u + 10) * (W_ + 1)] - cp[(pxb + u - 1) * (W_ + 1)];
                }
            }
        }
        __syncthreads();
        if (tid < 120) {
            int px = tid >> 2, q = tid & 3;
            float m = NINF;
            int d0 = q * 15, d1 = min(d0 + 15, ND);
            for (int d = d0; d < d1; ++d) m = fmaxf(m, scratch[px * SCW + d]);
            partials[tid] = m;
        }
        __syncthreads();
        if (tid < HP) {
            float m = fmaxf(fmaxf(partials[tid * 4], partials[tid * 4 + 1]),
                            fmaxf(partials[tid * 4 + 2], partials[tid * 4 + 3]));
            unsigned int ub = __float_as_uint(m);
            unsigned int k = (ub & 0x80000000u) ? ~ub : (ub | 0x80000000u);
            atomicMax(&keys[b * NL + py * HP + tid], k);
        }
        __syncthreads();
    }
}

// ===========================================================================
// k_decode: monotone uint keys -> float output
// ===========================================================================
__global__ __launch_bounds__(256)
void k_decode(const unsigned int* __restrict__ keys, float* __restrict__ out) {
    int i = blockIdx.x * 256 + threadIdx.x;
    if (i < NB * NL) {
        unsigned int k = keys[i];
        unsigned int u = (k & 0x80000000u) ? (k ^ 0x80000000u) : ~k;
        out[i] = __uint_as_float(u);
    }
}

// ===========================================================================
// Fallback path (R3) if ws_size is too small for G: k_norm_fb + k_main_fb
// ===========================================================================
__global__ __launch_bounds__(256)
void k_norm_fb(const float* __restrict__ im1, float* __restrict__ invnorm) {
    const int ly = blockIdx.x, b = blockIdx.y;
    const int tid = threadIdx.x;
    __shared__ float colsq[KS * W_];
    __shared__ float colsum[W_];
    const float* base = im1 + b * C_ * H_ * W_;
    for (int i = tid; i < KS * W_; i += 256) {
        int r = i / W_, x = i - r * W_;
        const float* p = base + (ly + r) * W_ + x;
        float s = 0.f;
        #pragma unroll 8
        for (int c = 0; c < C_; ++c) { float v = p[c * H_ * W_]; s += v * v; }
        colsq[i] = s;
    }
    __syncthreads();
    if (tid < W_) {
        float s = 0.f;
        #pragma unroll
        for (int r = 0; r < KS; ++r) s += colsq[r * W_ + tid];
        colsum[tid] = s;
    }
    __syncthreads();
    if (tid < HP) {
        float s = 0.f;
        #pragma unroll
        for (int sx = 0; sx < KS; ++sx) s += colsum[tid + sx];
        invnorm[b * NL + ly * HP + tid] = 1.f / fmaxf(sqrtf(s), EPSF);
    }
}

#define MAXPL 16
__global__ __launch_bounds__(256, 2)
void k_main_fb(const float* __restrict__ im1, const float* __restrict__ im2,
               const float* __restrict__ invnorm, unsigned int* __restrict__ keys) {
    const int chunk = blockIdx.x;
    const int dy = (int)blockIdx.y - (HP - 1);
    const int b = blockIdx.z;
    const int ady = dy < 0 ? -dy : dy;
    const int rows = HP - ady;
    if (chunk * PCH >= rows) return;
    const int pyLo = dy < 0 ? -dy : 0;
    const int py0 = pyLo + chunk * PCH;
    const int P = min(PCH, rows - chunk * PCH);
    const int nPl = P + KS - 1;
    const int tid = threadIdx.x;
    const int w = tid >> 6, L = tid & 63, lq = L >> 4, lr = L & 15;

    __shared__ __align__(16) _Float16 planes[MAXPL][H_ * W_];
    __shared__ __align__(16) float csum[H_ * W_];
    __shared__ __align__(16) _Float16 Astg[8][48][8];
    __shared__ __align__(16) _Float16 Bstg[8][48][8];
    __shared__ float scratch[HP * SCW];
    __shared__ float partials[120];
    __shared__ float sInv[HP];

    const float* im1b = im1 + b * C_ * H_ * W_;
    const float* im2b = im2 + b * C_ * H_ * W_;
    if (tid < 128) {
        int arr = tid >> 6, r = tid & 63;
        int oct = r >> 3, x = 40 + (r & 7);
        f16x8 z = {};
        *(f16x8*)((arr ? Bstg : Astg)[oct][x]) = z;
    }
    for (int p = 0; p < nPl; ++p) {
        const int y = py0 + p;
        for (int t = tid; t < 640; t += 256) {
            int arr = t >= 320;
            int r = arr ? t - 320 : t;
            int oct = r / 40, x = r - oct * 40;
            const float* pc = (arr ? (im1b + (y + dy) * W_) : (im2b + y * W_))
                              + oct * 8 * H_ * W_ + x;
            f16x8 h;
            #pragma unroll
            for (int j = 0; j < 8; ++j) h[j] = (_Float16)pc[j * H_ * W_];
            *(f16x8*)((arr ? Bstg : Astg)[oct][x]) = h;
        }
        __syncthreads();
        for (int t = w; t < 9; t += 4) {
            int mt = t / 3, nt = t - 3 * mt;
            f16x8 a0 = *(const f16x8*)(Astg[lq][mt * 16 + lr]);
            f16x8 b0 = *(const f16x8*)(Bstg[lq][nt * 16 + lr]);
            f16x8 a1 = *(const f16x8*)(Astg[4 + lq][mt * 16 + lr]);
            f16x8 b1 = *(const f16x8*)(Bstg[4 + lq][nt * 16 + lr]);
            f32x4 acc = {0.f, 0.f, 0.f, 0.f};
            acc = __builtin_amdgcn_mfma_f32_16x16x32_f16(a0, b0, acc, 0, 0, 0);
            acc = __builtin_amdgcn_mfma_f32_16x16x32_f16(a1, b1, acc, 0, 0, 0);
            int x1 = nt * 16 + lr;
            if (x1 < W_) {
                int x2b = mt * 16 + lq * 4;
                #pragma unroll
                for (int rg = 0; rg < 4; ++rg) {
                    int x2 = x2b + rg;
                    if (x2 < W_) planes[p][x2 * W_ + x1] = (_Float16)acc[rg];
                }
            }
        }
        __syncthreads();
    }
    for (int i = 0; i < P; ++i) {
        const int py = py0 + i, ly = py + dy;
        if (tid < 200) {
            float4* c4 = (float4*)(csum + tid * 8);
            if (i == 0) {
                float s[8] = {0.f,0.f,0.f,0.f,0.f,0.f,0.f,0.f};
                #pragma unroll
                for (int r = 0; r < KS; ++r) {
                    f16x8 q = *(const f16x8*)(planes[r] + tid * 8);
                    #pragma unroll
                    for (int j = 0; j < 8; ++j) s[j] += (float)q[j];
                }
                c4[0] = make_float4(s[0], s[1], s[2], s[3]);
                c4[1] = make_float4(s[4], s[5], s[6], s[7]);
            } else {
                f16x8 qa = *(const f16x8*)(planes[i + 10] + tid * 8);
                f16x8 qs = *(const f16x8*)(planes[i - 1] + tid * 8);
                float4 v0 = c4[0], v1 = c4[1];
                v0.x += (float)qa[0] - (float)qs[0]; v0.y += (float)qa[1] - (float)qs[1];
                v0.z += (float)qa[2] - (float)qs[2]; v0.w += (float)qa[3] - (float)qs[3];
                v1.x += (float)qa[4] - (float)qs[4]; v1.y += (float)qa[5] - (float)qs[5];
                v1.z += (float)qa[6] - (float)qs[6]; v1.w += (float)qa[7] - (float)qs[7];
                c4[0] = v0; c4[1] = v1;
            }
        } else if (tid >= 224 && tid < 224 + HP) {
            sInv[tid - 224] = invnorm[b * NL + ly * HP + (tid - 224)];
        }
        __syncthreads();
        for (int t = tid; t < 5 * ND; t += 256) {
            int pg = t / ND, dxI = t - ND * pg;
            int dx = dxI - (HP - 1), pxb = 6 * pg;
            #pragma unroll
            for (int u = 0; u < 6; ++u) scratch[(pxb + u) * SCW + dxI] = NINF;
            int u0 = max(0, -dx - pxb), u1 = min(5, (HP - 1) - dx - pxb);
            if (u0 <= u1) {
                const float* cp = csum + dx;
                float run = 0.f;
                #pragma unroll
                for (int sr = 0; sr < KS; ++sr) run += cp[(pxb + u0 + sr) * (W_ + 1)];
                int u = u0;
                for (;;) {
                    scratch[(pxb + u) * SCW + dxI] = run * sInv[pxb + u + dx];
                    if (++u > u1) break;
                    run += cp[(pxb + u + 10) * (W_ + 1)] - cp[(pxb + u - 1) * (W_ + 1)];
                }
            }
        }
        __syncthreads();
        if (tid < 120) {
            int px = tid >> 2, q = tid & 3;
            float m = NINF;
            int d0 = q * 15, d1 = min(d0 + 15, ND);
            for (int d = d0; d < d1; ++d) m = fmaxf(m, scratch[px * SCW + d]);
            partials[tid] = m;
        }
        __syncthreads();
        if (tid < HP) {
            float m = fmaxf(fmaxf(partials[tid * 4], partials[tid * 4 + 1]),
                            fmaxf(partials[tid * 4 + 2], partials[tid * 4 + 3]));
            unsigned int ub = __float_as_uint(m);
            unsigned int k = (ub & 0x80000000u) ? ~ub : (ub | 0x80000000u);
            atomicMax(&keys[b * NL + py * HP + tid], k);
        }
        __syncthreads();
    }
}

extern "C" void kernel_launch(void* const* d_in, const int* in_sizes, int n_in,
                              void* d_out, int out_size, void* d_ws, size_t ws_size,
                              hipStream_t stream) {
    const float* im1 = (const float*)d_in[0];
    const float* im2 = (const float*)d_in[1];
    unsigned int* keys = (unsigned int*)d_ws;                 // 14400 B
    float* invnorm = (float*)d_ws + NB * NL;                  // 14400 B
    // packed @ 32768, G @ 32768 + 1703936
    const size_t packedOff = 32768;
    const size_t packedBytes = (size_t)2 * NB * 8 * MPAD * 8 * 2;   // 1,703,936
    const size_t gOff = packedOff + packedBytes;                     // 1,736,704
    const size_t gBytes = (size_t)NB * MPAD * MPAD * 2;              // 22,151,168
    const size_t needed = gOff + gBytes;

    hipMemsetAsync(d_ws, 0, NB * NL * sizeof(unsigned int), stream);
    if (ws_size >= needed) {
        _Float16* packed = (_Float16*)((char*)d_ws + packedOff);
        _Float16* G = (_Float16*)((char*)d_ws + gOff);
        k_pack<<<dim3(NB, 2), 1024, 0, stream>>>(im2, im1, packed, invnorm);
        k_gram<<<dim3(13, 13, NB), 256, 0, stream>>>(packed, G);
        k_box<<<dim3(5, ND, NB), 256, 0, stream>>>(G, invnorm, keys);
    } else {
        k_norm_fb<<<dim3(HP, NB), 256, 0, stream>>>(im1, invnorm);
        k_main_fb<<<dim3(5, ND, NB), 256, 0, stream>>>(im1, im2, invnorm, keys);
    }
    k_decode<<<(NB * NL + 255) / 256, 256, 0, stream>>>(keys, (float*)d_out);
}

// Round 6
// 103.019 us; speedup vs baseline: 2.7325x; 1.0704x over previous
//
#include <hip/hip_runtime.h>

#define C_    64
#define H_    40
#define W_    40
#define KS    11
#define HP    30          // H_ - KS + 1
#define NB    4
#define NL    900         // HP*HP
#define ND    59          // 2*(HP-1)+1
#define EPSF  1e-4f
#define PCH   6           // output rows per chunk in k_box
#define SCW   65          // scratch row stride (odd -> conflict-free)
#define NINF  -3.4e38f
#define MPAD  1664        // 13*128, padded M=N
#define GSTEP 66600       // 40*MPAD + 40: plane-to-plane step along the dy diagonal

typedef _Float16 f16x8 __attribute__((ext_vector_type(8)));
typedef float    f32x4 __attribute__((ext_vector_type(4)));

// ===========================================================================
// k_pack: fp32 images -> f16 octet-packed packed[img][b][oct][MPAD][8].
//         grid (13, NB, 2) x 128 threads; fully coalesced. img==1 also writes
//         per-pixel channel sum-of-squares; img==0 zeroes the keys buffer.
// ===========================================================================
__global__ __launch_bounds__(128)
void k_pack(const float* __restrict__ im2, const float* __restrict__ im1,
            _Float16* __restrict__ packed, float* __restrict__ ssqbuf,
            unsigned int* __restrict__ keys) {
    const int blk = blockIdx.x, b = blockIdx.y, img = blockIdx.z;
    const int pos = blk * 128 + threadIdx.x;       // 0..1663
    const float* src = (img ? im1 : im2) + b * C_ * 1600;
    _Float16* dst = packed + ((size_t)img * NB + b) * (8 * MPAD * 8);
    float ss = 0.f;
    #pragma unroll
    for (int oct = 0; oct < 8; ++oct) {
        f16x8 h = {};
        if (pos < 1600) {
            #pragma unroll
            for (int j = 0; j < 8; ++j) {
                float v = src[(oct * 8 + j) * 1600 + pos];
                h[j] = (_Float16)v;
                ss += v * v;
            }
        }
        *(f16x8*)&dst[(oct * MPAD + pos) * 8] = h;
    }
    if (img == 1 && pos < 1600) ssqbuf[b * 1600 + pos] = ss;
    if (img == 0 && pos < NL) keys[b * NL + pos] = 0u;
}

// ===========================================================================
// k_norm: separable 11x11 box filter of ssq -> invnorm. grid (NB) x 1024.
// ===========================================================================
__global__ __launch_bounds__(1024)
void k_norm(const float* __restrict__ ssqbuf, float* __restrict__ invnorm) {
    const int b = blockIdx.x, tid = threadIdx.x;
    __shared__ float ssq[1600];
    __shared__ float colsum[1200];
    for (int i = tid; i < 1600; i += 1024) ssq[i] = ssqbuf[b * 1600 + i];
    __syncthreads();
    for (int t = tid; t < HP * W_; t += 1024) {
        int yy = t / W_, x = t - yy * W_;
        float s = 0.f;
        #pragma unroll
        for (int r = 0; r < KS; ++r) s += ssq[(yy + r) * W_ + x];
        colsum[t] = s;
    }
    __syncthreads();
    for (int t = tid; t < NL; t += 1024) {
        int ly = t / HP, lx = t - ly * HP;
        float s = 0.f;
        #pragma unroll
        for (int sx = 0; sx < KS; ++sx) s += colsum[ly * W_ + lx + sx];
        invnorm[b * NL + t] = 1.f / fmaxf(sqrtf(s), EPSF);
    }
}

// ===========================================================================
// k_gram: G[b][m][n] = sum_c im2[c][m] * im1[c][n], f16 out, stride MPAD.
// 128x128 tile per block, 256 threads (4 waves x 64x64), K=64 single shot.
// Only the |i-j| <= 10 tile band is needed (|n-m| <= 1199).
// ===========================================================================
__global__ __launch_bounds__(256, 3)
void k_gram(const _Float16* __restrict__ packed, _Float16* __restrict__ G) {
    const int i = blockIdx.x, j = blockIdx.y, b = blockIdx.z;
    int dd = i - j; if (dd < 0) dd = -dd;
    if (dd > 10) return;
    const int tid = threadIdx.x;
    const int w = tid >> 6, L = tid & 63, lq = L >> 4, lr = L & 15;

    __shared__ __align__(16) _Float16 smem[128 * 136];   // A(16K)+B(16K) / C overlay
    _Float16 (*As)[128][8] = (_Float16 (*)[128][8])smem;
    _Float16 (*Bs)[128][8] = (_Float16 (*)[128][8])(smem + 8192);

    const _Float16* pa = packed + (size_t)b * (8 * MPAD * 8);
    const _Float16* pb = packed + (size_t)(NB + b) * (8 * MPAD * 8);
    for (int t = tid; t < 1024; t += 256) {
        int oct = t >> 7, m = t & 127;
        *(f16x8*)&As[oct][m][0] = *(const f16x8*)&pa[(oct * MPAD + i * 128 + m) * 8];
        *(f16x8*)&Bs[oct][m][0] = *(const f16x8*)&pb[(oct * MPAD + j * 128 + m) * 8];
    }
    __syncthreads();

    const int mb = (w & 1) * 64, nb = (w >> 1) * 64;
    f16x8 a0[4], a1[4], b0[4], b1[4];
    #pragma unroll
    for (int q = 0; q < 4; ++q) {
        a0[q] = *(const f16x8*)&As[lq][mb + q * 16 + lr][0];
        a1[q] = *(const f16x8*)&As[4 + lq][mb + q * 16 + lr][0];
        b0[q] = *(const f16x8*)&Bs[lq][nb + q * 16 + lr][0];
        b1[q] = *(const f16x8*)&Bs[4 + lq][nb + q * 16 + lr][0];
    }
    f32x4 acc[4][4];
    #pragma unroll
    for (int mi = 0; mi < 4; ++mi)
        #pragma unroll
        for (int ni = 0; ni < 4; ++ni) {
            f32x4 c = {0.f, 0.f, 0.f, 0.f};
            c = __builtin_amdgcn_mfma_f32_16x16x32_f16(a0[mi], b0[ni], c, 0, 0, 0);
            c = __builtin_amdgcn_mfma_f32_16x16x32_f16(a1[mi], b1[ni], c, 0, 0, 0);
            acc[mi][ni] = c;
        }
    __syncthreads();   // frags in regs; safe to overlay C on smem
    // C layout: row (A/m) = quad*4+reg, col (B/n) = lane&15
    #pragma unroll
    for (int mi = 0; mi < 4; ++mi)
        #pragma unroll
        for (int ni = 0; ni < 4; ++ni)
            #pragma unroll
            for (int rg = 0; rg < 4; ++rg)
                smem[(mb + mi * 16 + lq * 4 + rg) * 136 + nb + ni * 16 + lr] =
                    (_Float16)acc[mi][ni][rg];
    __syncthreads();
    _Float16* Gb = G + (size_t)b * (MPAD * MPAD);
    for (int t = tid; t < 2048; t += 256) {
        int row = t >> 4, seg = t & 15;
        *(f16x8*)&Gb[(size_t)(i * 128 + row) * MPAD + j * 128 + seg * 8] =
            *(const f16x8*)&smem[row * 136 + seg * 8];
    }
}

// ===========================================================================
// k_box: per (chunk, dy, b) — register-resident sliding column sums over G
// planes (prefetched one row ahead) + diagonal 11-tap sums + max over dx.
// Slide at iteration i (i>0) consumes qa=plane[i+10], qs=plane[i-1]; the
// prefetch issued at iteration i for use at i+1 loads plane[i+11], plane[i].
// ===========================================================================
__global__ __launch_bounds__(256, 4)
void k_box(const _Float16* __restrict__ G, const float* __restrict__ invnorm,
           unsigned int* __restrict__ keys) {
    const int chunk = blockIdx.x;
    const int dy = (int)blockIdx.y - (HP - 1);
    const int b = blockIdx.z;
    const int ady = dy < 0 ? -dy : dy;
    const int rows = HP - ady;
    if (chunk * PCH >= rows) return;
    const int pyLo = dy < 0 ? -dy : 0;
    const int py0 = pyLo + chunk * PCH;
    const int P = min(PCH, rows - chunk * PCH);
    const int tid = threadIdx.x;

    __shared__ float csum[1600];
    __shared__ float scratch[HP * SCW];
    __shared__ float partials[120];
    __shared__ float sInvAll[PCH][HP];

    // preload all invnorm rows for this chunk (used after sync A)
    if (tid < P * HP) {
        int i = tid / HP, lx = tid - i * HP;
        sInvAll[i][lx] = invnorm[b * NL + (py0 + i + dy) * HP + lx];
    }

    const _Float16* Gb = G + (size_t)b * (MPAD * MPAD);
    float s[8];
    f16x8 qa, qs;
    const _Float16* base = nullptr;
    if (tid < 200) {
        int e = tid * 8, x2 = e / 40, x1 = e - x2 * 40;
        base = Gb + (size_t)py0 * GSTEP + x2 * MPAD + dy * 40 + x1;
        #pragma unroll
        for (int j = 0; j < 8; ++j) s[j] = 0.f;
        for (int r = 0; r < KS; ++r) {
            f16x8 q = *(const f16x8*)(base + r * GSTEP);
            #pragma unroll
            for (int j = 0; j < 8; ++j) s[j] += (float)q[j];
        }
    }

    for (int i = 0; i < P; ++i) {
        const int py = py0 + i;
        if (tid < 200) {
            if (i > 0) {
                #pragma unroll
                for (int j = 0; j < 8; ++j) s[j] += (float)qa[j] - (float)qs[j];
            }
            float4* c4 = (float4*)(csum + tid * 8);
            c4[0] = make_float4(s[0], s[1], s[2], s[3]);
            c4[1] = make_float4(s[4], s[5], s[6], s[7]);
            if (i + 1 < P) {   // prefetch slide pair for iteration i+1
                qa = *(const f16x8*)(base + (i + 11) * GSTEP);
                qs = *(const f16x8*)(base + i * GSTEP);
            }
        }
        __syncthreads();                                   // A
        // diagonal 11-tap running sums: task = (px-group of 6, dx)
        for (int t = tid; t < 5 * ND; t += 256) {
            int pg = t / ND, dxI = t - ND * pg;
            int dx = dxI - (HP - 1), pxb = 6 * pg;
            #pragma unroll
            for (int u = 0; u < 6; ++u) scratch[(pxb + u) * SCW + dxI] = NINF;
            int u0 = max(0, -dx - pxb), u1 = min(5, (HP - 1) - dx - pxb);
            if (u0 <= u1) {
                const float* cp = csum + dx;
                float run = 0.f;
                #pragma unroll
                for (int sr = 0; sr < KS; ++sr) run += cp[(pxb + u0 + sr) * (W_ + 1)];
                int u = u0;
                for (;;) {
                    scratch[(pxb + u) * SCW + dxI] = run * sInvAll[i][pxb + u + dx];
                    if (++u > u1) break;
                    run += cp[(pxb + u + 10) * (W_ + 1)] - cp[(pxb + u - 1) * (W_ + 1)];
                }
            }
        }
        __syncthreads();                                   // B
        if (tid < 120) {
            int px = tid >> 2, q = tid & 3;
            float m = NINF;
            int d0 = q * 15, d1 = min(d0 + 15, ND);
            for (int d = d0; d < d1; ++d) m = fmaxf(m, scratch[px * SCW + d]);
            partials[tid] = m;
        }
        __syncthreads();                                   // C
        if (tid < HP) {
            float m = fmaxf(fmaxf(partials[tid * 4], partials[tid * 4 + 1]),
                            fmaxf(partials[tid * 4 + 2], partials[tid * 4 + 3]));
            unsigned int ub = __float_as_uint(m);
            unsigned int k = (ub & 0x80000000u) ? ~ub : (ub | 0x80000000u);
            atomicMax(&keys[b * NL + py * HP + tid], k);
        }
        // no trailing sync needed: sync C orders all csum/scratch/partials rewrites
    }
}

// ===========================================================================
// k_decode: monotone uint keys -> float output
// ===========================================================================
__global__ __launch_bounds__(256)
void k_decode(const unsigned int* __restrict__ keys, float* __restrict__ out) {
    int i = blockIdx.x * 256 + threadIdx.x;
    if (i < NB * NL) {
        unsigned int k = keys[i];
        unsigned int u = (k & 0x80000000u) ? (k ^ 0x80000000u) : ~k;
        out[i] = __uint_as_float(u);
    }
}

// ===========================================================================
// Fallback path (no big ws): R3 structure
// ===========================================================================
__global__ __launch_bounds__(256)
void k_norm_fb(const float* __restrict__ im1, float* __restrict__ invnorm) {
    const int ly = blockIdx.x, b = blockIdx.y;
    const int tid = threadIdx.x;
    __shared__ float colsq[KS * W_];
    __shared__ float colsum[W_];
    const float* base = im1 + b * C_ * H_ * W_;
    for (int i = tid; i < KS * W_; i += 256) {
        int r = i / W_, x = i - r * W_;
        const float* p = base + (ly + r) * W_ + x;
        float s = 0.f;
        #pragma unroll 8
        for (int c = 0; c < C_; ++c) { float v = p[c * H_ * W_]; s += v * v; }
        colsq[i] = s;
    }
    __syncthreads();
    if (tid < W_) {
        float s = 0.f;
        #pragma unroll
        for (int r = 0; r < KS; ++r) s += colsq[r * W_ + tid];
        colsum[tid] = s;
    }
    __syncthreads();
    if (tid < HP) {
        float s = 0.f;
        #pragma unroll
        for (int sx = 0; sx < KS; ++sx) s += colsum[tid + sx];
        invnorm[b * NL + ly * HP + tid] = 1.f / fmaxf(sqrtf(s), EPSF);
    }
}

#define MAXPL 16
__global__ __launch_bounds__(256, 2)
void k_main_fb(const float* __restrict__ im1, const float* __restrict__ im2,
               const float* __restrict__ invnorm, unsigned int* __restrict__ keys) {
    const int chunk = blockIdx.x;
    const int dy = (int)blockIdx.y - (HP - 1);
    const int b = blockIdx.z;
    const int ady = dy < 0 ? -dy : dy;
    const int rows = HP - ady;
    if (chunk * PCH >= rows) return;
    const int pyLo = dy < 0 ? -dy : 0;
    const int py0 = pyLo + chunk * PCH;
    const int P = min(PCH, rows - chunk * PCH);
    const int nPl = P + KS - 1;
    const int tid = threadIdx.x;
    const int w = tid >> 6, L = tid & 63, lq = L >> 4, lr = L & 15;

    __shared__ __align__(16) _Float16 planes[MAXPL][H_ * W_];
    __shared__ __align__(16) float csum[H_ * W_];
    __shared__ __align__(16) _Float16 Astg[8][48][8];
    __shared__ __align__(16) _Float16 Bstg[8][48][8];
    __shared__ float scratch[HP * SCW];
    __shared__ float partials[120];
    __shared__ float sInv[HP];

    const float* im1b = im1 + b * C_ * H_ * W_;
    const float* im2b = im2 + b * C_ * H_ * W_;
    if (tid < 128) {
        int arr = tid >> 6, r = tid & 63;
        int oct = r >> 3, x = 40 + (r & 7);
        f16x8 z = {};
        *(f16x8*)((arr ? Bstg : Astg)[oct][x]) = z;
    }
    for (int p = 0; p < nPl; ++p) {
        const int y = py0 + p;
        for (int t = tid; t < 640; t += 256) {
            int arr = t >= 320;
            int r = arr ? t - 320 : t;
            int oct = r / 40, x = r - oct * 40;
            const float* pc = (arr ? (im1b + (y + dy) * W_) : (im2b + y * W_))
                              + oct * 8 * H_ * W_ + x;
            f16x8 h;
            #pragma unroll
            for (int j = 0; j < 8; ++j) h[j] = (_Float16)pc[j * H_ * W_];
            *(f16x8*)((arr ? Bstg : Astg)[oct][x]) = h;
        }
        __syncthreads();
        for (int t = w; t < 9; t += 4) {
            int mt = t / 3, nt = t - 3 * mt;
            f16x8 a0 = *(const f16x8*)(Astg[lq][mt * 16 + lr]);
            f16x8 b0 = *(const f16x8*)(Bstg[lq][nt * 16 + lr]);
            f16x8 a1 = *(const f16x8*)(Astg[4 + lq][mt * 16 + lr]);
            f16x8 b1 = *(const f16x8*)(Bstg[4 + lq][nt * 16 + lr]);
            f32x4 acc = {0.f, 0.f, 0.f, 0.f};
            acc = __builtin_amdgcn_mfma_f32_16x16x32_f16(a0, b0, acc, 0, 0, 0);
            acc = __builtin_amdgcn_mfma_f32_16x16x32_f16(a1, b1, acc, 0, 0, 0);
            int x1 = nt * 16 + lr;
            if (x1 < W_) {
                int x2b = mt * 16 + lq * 4;
                #pragma unroll
                for (int rg = 0; rg < 4; ++rg) {
                    int x2 = x2b + rg;
                    if (x2 < W_) planes[p][x2 * W_ + x1] = (_Float16)acc[rg];
                }
            }
        }
        __syncthreads();
    }
    for (int i = 0; i < P; ++i) {
        const int py = py0 + i, ly = py + dy;
        if (tid < 200) {
            float4* c4 = (float4*)(csum + tid * 8);
            if (i == 0) {
                float s[8] = {0.f,0.f,0.f,0.f,0.f,0.f,0.f,0.f};
                #pragma unroll
                for (int r = 0; r < KS; ++r) {
                    f16x8 q = *(const f16x8*)(planes[r] + tid * 8);
                    #pragma unroll
                    for (int j = 0; j < 8; ++j) s[j] += (float)q[j];
                }
                c4[0] = make_float4(s[0], s[1], s[2], s[3]);
                c4[1] = make_float4(s[4], s[5], s[6], s[7]);
            } else {
                f16x8 qa = *(const f16x8*)(planes[i + 10] + tid * 8);
                f16x8 qs = *(const f16x8*)(planes[i - 1] + tid * 8);
                float4 v0 = c4[0], v1 = c4[1];
                v0.x += (float)qa[0] - (float)qs[0]; v0.y += (float)qa[1] - (float)qs[1];
                v0.z += (float)qa[2] - (float)qs[2]; v0.w += (float)qa[3] - (float)qs[3];
                v1.x += (float)qa[4] - (float)qs[4]; v1.y += (float)qa[5] - (float)qs[5];
                v1.z += (float)qa[6] - (float)qs[6]; v1.w += (float)qa[7] - (float)qs[7];
                c4[0] = v0; c4[1] = v1;
            }
        } else if (tid >= 224 && tid < 224 + HP) {
            sInv[tid - 224] = invnorm[b * NL + ly * HP + (tid - 224)];
        }
        __syncthreads();
        for (int t = tid; t < 5 * ND; t += 256) {
            int pg = t / ND, dxI = t - ND * pg;
            int dx = dxI - (HP - 1), pxb = 6 * pg;
            #pragma unroll
            for (int u = 0; u < 6; ++u) scratch[(pxb + u) * SCW + dxI] = NINF;
            int u0 = max(0, -dx - pxb), u1 = min(5, (HP - 1) - dx - pxb);
            if (u0 <= u1) {
                const float* cp = csum + dx;
                float run = 0.f;
                #pragma unroll
                for (int sr = 0; sr < KS; ++sr) run += cp[(pxb + u0 + sr) * (W_ + 1)];
                int u = u0;
                for (;;) {
                    scratch[(pxb + u) * SCW + dxI] = run * sInv[pxb + u + dx];
                    if (++u > u1) break;
                    run += cp[(pxb + u + 10) * (W_ + 1)] - cp[(pxb + u - 1) * (W_ + 1)];
                }
            }
        }
        __syncthreads();
        if (tid < 120) {
            int px = tid >> 2, q = tid & 3;
            float m = NINF;
            int d0 = q * 15, d1 = min(d0 + 15, ND);
            for (int d = d0; d < d1; ++d) m = fmaxf(m, scratch[px * SCW + d]);
            partials[tid] = m;
        }
        __syncthreads();
        if (tid < HP) {
            float m = fmaxf(fmaxf(partials[tid * 4], partials[tid * 4 + 1]),
                            fmaxf(partials[tid * 4 + 2], partials[tid * 4 + 3]));
            unsigned int ub = __float_as_uint(m);
            unsigned int k = (ub & 0x80000000u) ? ~ub : (ub | 0x80000000u);
            atomicMax(&keys[b * NL + py * HP + tid], k);
        }
        __syncthreads();
    }
}

extern "C" void kernel_launch(void* const* d_in, const int* in_sizes, int n_in,
                              void* d_out, int out_size, void* d_ws, size_t ws_size,
                              hipStream_t stream) {
    const float* im1 = (const float*)d_in[0];
    const float* im2 = (const float*)d_in[1];
    unsigned int* keys = (unsigned int*)d_ws;                 // 14400 B @ 0
    float* invnorm = (float*)((char*)d_ws + 14400);           // 14400 B
    float* ssqbuf  = (float*)((char*)d_ws + 28800);           // 25600 B
    const size_t packedOff = 65536;
    const size_t packedBytes = (size_t)2 * NB * 8 * MPAD * 8 * 2;   // 1,703,936
    const size_t gOff = packedOff + packedBytes;
    const size_t gBytes = (size_t)NB * MPAD * MPAD * 2;              // 22,151,168
    const size_t needed = gOff + gBytes;

    if (ws_size >= needed) {
        _Float16* packed = (_Float16*)((char*)d_ws + packedOff);
        _Float16* G = (_Float16*)((char*)d_ws + gOff);
        k_pack<<<dim3(13, NB, 2), 128, 0, stream>>>(im2, im1, packed, ssqbuf, keys);
        k_norm<<<NB, 1024, 0, stream>>>(ssqbuf, invnorm);
        k_gram<<<dim3(13, 13, NB), 256, 0, stream>>>(packed, G);
        k_box<<<dim3(5, ND, NB), 256, 0, stream>>>(G, invnorm, keys);
    } else {
        hipMemsetAsync(d_ws, 0, NB * NL * sizeof(unsigned int), stream);
        k_norm_fb<<<dim3(HP, NB), 256, 0, stream>>>(im1, invnorm);
        k_main_fb<<<dim3(5, ND, NB), 256, 0, stream>>>(im1, im2, invnorm, keys);
    }
    k_decode<<<(NB * NL + 255) / 256, 256, 0, stream>>>(keys, (float*)d_out);
}